// Round 13
// baseline (492.013 us; speedup 1.0000x reference)
//
#include <hip/hip_runtime.h>

#define BS 32
#define Nn 2048
#define Ww 128
#define Rr 8
#define EPSF 1e-8f

#define TI   128     // rows per link tile
#define NT   16      // Nn/TI row tiles
#define WCH  32      // cols per chunk
#define NCHL 32      // chunks per block (col-half = 1024 cols)

// workspace layout (float offsets)
#define OFF_WW      0
#define OFF_MEMNEW  (OFF_WW + BS*Nn)
#define OFF_MEMNORM (OFF_MEMNEW + Nn*Ww)
#define OFF_CR      (OFF_MEMNORM + Nn)
#define OFF_M2      (OFF_CR + BS*Nn*Rr)
#define OFF_O1      (OFF_M2 + BS*Nn*16)             // 2 sets (col halves)
#define OFF_C12     (OFF_O1 + 2*BS*Nn*16)
#define OFF_PART    (OFF_C12 + BS*16)
#define OFF_SIM     (OFF_PART + NT*BS*Nn*16)

__device__ __forceinline__ void gload_lds16(const void* g, void* l) {
    __builtin_amdgcn_global_load_lds((const __attribute__((address_space(1))) void*)g,
                                     (__attribute__((address_space(3))) void*)l, 16, 0, 0);
}

#define FMA16(ACC, LV, M0, M1, M2V, M3) \
    ACC[0]  += (LV)*(M0).x;  ACC[1]  += (LV)*(M0).y;  ACC[2]  += (LV)*(M0).z;  ACC[3]  += (LV)*(M0).w; \
    ACC[4]  += (LV)*(M1).x;  ACC[5]  += (LV)*(M1).y;  ACC[6]  += (LV)*(M1).z;  ACC[7]  += (LV)*(M1).w; \
    ACC[8]  += (LV)*(M2V).x; ACC[9]  += (LV)*(M2V).y; ACC[10] += (LV)*(M2V).z; ACC[11] += (LV)*(M2V).w; \
    ACC[12] += (LV)*(M3).x;  ACC[13] += (LV)*(M3).y;  ACC[14] += (LV)*(M3).z;  ACC[15] += (LV)*(M3).w;

// ---------------------------------------------------------------- K0: write-content similarity (256 blocks)
__global__ __launch_bounds__(256) void k_sim(const float* __restrict__ mem,
    const float* __restrict__ wkey, const float* __restrict__ wstr,
    float* __restrict__ simg)
{
    __shared__ float sWK[Ww];
    const int b = blockIdx.x >> 3, sl = blockIdx.x & 7;
    const int tx = threadIdx.x;
    if (tx < Ww) sWK[tx] = wkey[b*Ww + tx];
    __syncthreads();
    float wn2 = 0.f;
    #pragma unroll
    for (int w = 0; w < Ww; w += 4) {
        float4 k4 = *(const float4*)(&sWK[w]);
        wn2 += k4.x*k4.x + k4.y*k4.y + k4.z*k4.z + k4.w*k4.w;
    }
    const float wn = sqrtf(wn2);
    const float st = wstr[b];
    const int n = sl*256 + tx;
    const float* mrow = mem + (size_t)n*Ww;
    float dot = 0.f, m2 = 0.f;
    #pragma unroll
    for (int w = 0; w < Ww; w += 4) {
        float4 m4 = *(const float4*)(mrow + w);
        float4 k4 = *(const float4*)(&sWK[w]);
        dot += m4.x*k4.x + m4.y*k4.y + m4.z*k4.z + m4.w*k4.w;
        m2  += m4.x*m4.x + m4.y*m4.y + m4.z*m4.z + m4.w*m4.w;
    }
    float denom = fmaxf(sqrtf(m2)*wn, EPSF);
    simg[b*Nn + n] = dot / denom * st;
}

// ---------------------------------------------------------------- K1: sort(u64) + alloc + softmax(sim) + ww + prep
__global__ __launch_bounds__(512) void k_front(const float* __restrict__ usage,
    const float* __restrict__ simg, const float* __restrict__ agate,
    const float* __restrict__ wgate, const float* __restrict__ lrw,
    const float* __restrict__ prec, float* __restrict__ ww_out,
    float* __restrict__ M2, float* __restrict__ c12)
{
    __shared__ unsigned long long sk[Nn];   // 16 KB packed (value_bits<<32)|index
    __shared__ float sAll[Nn];              // 8 KB alloc_sorted
    __shared__ float sSim[Nn];              // 8 KB
    __shared__ float sRed[512];
    __shared__ float sQ[64];
    __shared__ float sC[8][16];
    const int b = blockIdx.x, tx = threadIdx.x;

    #pragma unroll
    for (int m = 0; m < 4; ++m) {
        int i = m*512 + tx;
        sk[i] = ((unsigned long long)__float_as_uint(usage[b*Nn + i]) << 32) | (unsigned)i;
    }
    __syncthreads();
    for (int k = 2; k <= Nn; k <<= 1) {
        for (int j = k >> 1; j > 0; j >>= 1) {
            #pragma unroll
            for (int m = 0; m < 4; ++m) {
                int i = m*512 + tx;
                int ixj = i ^ j;
                if (ixj > i) {
                    bool up = ((i & k) == 0);
                    unsigned long long a = sk[i], c = sk[ixj];
                    if (up ? (a > c) : (a < c)) { sk[i] = c; sk[ixj] = a; }
                }
            }
            __syncthreads();
        }
    }
    {
        float p = 1.f;
        #pragma unroll
        for (int e = 0; e < 4; ++e)
            p *= __uint_as_float((unsigned)(sk[tx*4 + e] >> 32));
        sRed[tx] = p;
        __syncthreads();
        if (tx < 64) {
            float q = 1.f;
            #pragma unroll
            for (int e = 0; e < 8; ++e) q *= sRed[tx*8 + e];
            sQ[tx] = q;
        }
        __syncthreads();
        if (tx == 0) {
            float run = 1.f;
            for (int s = 0; s < 64; ++s) { float t = sQ[s]; sQ[s] = run; run *= t; }
        }
        __syncthreads();
        float run = sQ[tx >> 3];
        for (int s = (tx & ~7); s < tx; ++s) run *= sRed[s];
        #pragma unroll
        for (int e = 0; e < 4; ++e) {
            float v = __uint_as_float((unsigned)(sk[tx*4 + e] >> 32));
            sAll[tx*4 + e] = (1.f - v) * run;
            run *= v;
        }
    }
    #pragma unroll
    for (int m = 0; m < 4; ++m) {
        int n = m*512 + tx;
        sSim[n] = simg[b*Nn + n];
    }
    __syncthreads();
    float allocr[4];
    #pragma unroll
    for (int m = 0; m < 4; ++m) {
        int i = m*512 + tx;
        allocr[m] = sAll[(unsigned)(sk[i] & 0xffffffffu)];
    }
    float lm = -3.402823466e38f;
    #pragma unroll
    for (int m = 0; m < 4; ++m) lm = fmaxf(lm, sSim[m*512 + tx]);
    sRed[tx] = lm; __syncthreads();
    for (int s = 256; s > 0; s >>= 1) { if (tx < s) sRed[tx] = fmaxf(sRed[tx], sRed[tx+s]); __syncthreads(); }
    float mx = sRed[0]; __syncthreads();
    float ls = 0.f;
    #pragma unroll
    for (int m = 0; m < 4; ++m) ls += expf(sSim[m*512 + tx] - mx);
    sRed[tx] = ls; __syncthreads();
    for (int s = 256; s > 0; s >>= 1) { if (tx < s) sRed[tx] += sRed[tx+s]; __syncthreads(); }
    float inv = 1.f / sRed[0];
    float ag = agate[b], wg = wgate[b];
    float wwr[4];
    #pragma unroll
    for (int m = 0; m < 4; ++m) {
        int n = m*512 + tx;
        float cw = expf(sSim[n] - mx) * inv;
        wwr[m] = wg * (ag * allocr[m] + (1.f - ag) * cw);
        ww_out[b*Nn + n] = wwr[m];
    }

    float c1p[8] = {0,0,0,0,0,0,0,0};
    float c2p[8] = {0,0,0,0,0,0,0,0};
    #pragma unroll
    for (int m = 0; m < 4; ++m) {
        int j = m*512 + tx;
        size_t jb = (size_t)b*Nn + j;
        float4 a  = *(const float4*)(lrw + jb*Rr);
        float4 b4 = *(const float4*)(lrw + jb*Rr + 4);
        float w = wwr[m], pv = prec[jb];
        float* dst = M2 + jb*16;
        ((float4*)dst)[0] = a;
        ((float4*)dst)[1] = b4;
        ((float4*)dst)[2] = make_float4(a.x*w,  a.y*w,  a.z*w,  a.w*w);
        ((float4*)dst)[3] = make_float4(b4.x*w, b4.y*w, b4.z*w, b4.w*w);
        c1p[0] += pv*a.x;  c1p[1] += pv*a.y;  c1p[2] += pv*a.z;  c1p[3] += pv*a.w;
        c1p[4] += pv*b4.x; c1p[5] += pv*b4.y; c1p[6] += pv*b4.z; c1p[7] += pv*b4.w;
        c2p[0] += w*a.x;   c2p[1] += w*a.y;   c2p[2] += w*a.z;   c2p[3] += w*a.w;
        c2p[4] += w*b4.x;  c2p[5] += w*b4.y;  c2p[6] += w*b4.z;  c2p[7] += w*b4.w;
    }
    #pragma unroll
    for (int r = 0; r < 8; ++r) {
        float v1 = c1p[r], v2 = c2p[r];
        #pragma unroll
        for (int m = 1; m < 64; m <<= 1) { v1 += __shfl_xor(v1, m); v2 += __shfl_xor(v2, m); }
        c1p[r] = v1; c2p[r] = v2;
    }
    int wv = tx >> 6;
    if ((tx & 63) == 0) {
        #pragma unroll
        for (int r = 0; r < 8; ++r) { sC[wv][r] = c1p[r]; sC[wv][8+r] = c2p[r]; }
    }
    __syncthreads();
    if (tx < 16) {
        float s = 0.f;
        #pragma unroll
        for (int w8 = 0; w8 < 8; ++w8) s += sC[w8][tx];
        c12[b*16 + tx] = s;
    }
}

// ---------------------------------------------------------------- K2: memory_new + row norms
__global__ void k_memnew(const float* __restrict__ mem, const float* __restrict__ ww,
                         const float* __restrict__ erasev, const float* __restrict__ wvec,
                         float* __restrict__ memnew, float* __restrict__ memnorm)
{
    __shared__ float s_red[2][Ww];
    int tx = threadIdx.x;
    int h = tx >> 7, w = tx & 127;
    int n = blockIdx.x * 2 + h;
    float accE = 0.f, accA = 0.f;
    for (int b = 0; b < BS; ++b) {
        float wwv = ww[b*Nn + n];
        accE += wwv * erasev[b*Ww + w];
        accA += wwv * wvec[b*Ww + w];
    }
    const float inv = 1.f / (float)BS;
    float m = mem[(size_t)n*Ww + w];
    float outv = m * (1.f - accE*inv) + accA*inv;
    memnew[(size_t)n*Ww + w] = outv;
    s_red[h][w] = outv*outv;
    __syncthreads();
    for (int s = 64; s > 0; s >>= 1) { if (w < s) s_red[h][w] += s_red[h][w+s]; __syncthreads(); }
    if (w == 0) memnorm[n] = sqrtf(s_red[h][0]);
}

// ---------------------------------------------------------------- K3a: read-sim dots (memnew read ONCE per block)
__global__ __launch_bounds__(256) void k_crdot(const float* __restrict__ memnew,
    const float* __restrict__ memnorm, const float* __restrict__ rkeys,
    const float* __restrict__ rstr, float* __restrict__ crbuf)
{
    __shared__ float sK[Ww][Rr];    // 4 KB keys
    __shared__ float sKn[Rr];
    __shared__ float sSt[Rr];
    const int b = blockIdx.x >> 3, sl = blockIdx.x & 7;
    const int tx = threadIdx.x;
    for (int k = tx; k < Ww*Rr; k += 256) {
        int w = k >> 3, r = k & 7;
        sK[w][r] = rkeys[((size_t)b*Ww + w)*Rr + r];
    }
    if (tx < Rr) sSt[tx] = rstr[b*Rr + tx];
    __syncthreads();
    if (tx < Rr) {
        float kn2 = 0.f;
        for (int w = 0; w < Ww; ++w) { float k = sK[w][tx]; kn2 += k*k; }
        sKn[tx] = sqrtf(kn2);
    }
    __syncthreads();
    const int n = sl*256 + tx;
    const float* mrow = memnew + (size_t)n*Ww;
    float dot[8] = {0,0,0,0,0,0,0,0};
    #pragma unroll 4
    for (int w = 0; w < Ww; w += 4) {
        float4 m4 = *(const float4*)(mrow + w);
        #pragma unroll
        for (int l = 0; l < 4; ++l) {
            float mv = (l==0)?m4.x:(l==1)?m4.y:(l==2)?m4.z:m4.w;
            float4 k0 = *(const float4*)(&sK[w+l][0]);
            float4 k1 = *(const float4*)(&sK[w+l][4]);
            dot[0] += mv*k0.x; dot[1] += mv*k0.y; dot[2] += mv*k0.z; dot[3] += mv*k0.w;
            dot[4] += mv*k1.x; dot[5] += mv*k1.y; dot[6] += mv*k1.z; dot[7] += mv*k1.w;
        }
    }
    const float mn = memnorm[n];
    float simv[8];
    #pragma unroll
    for (int r = 0; r < 8; ++r)
        simv[r] = dot[r] / fmaxf(mn*sKn[r], EPSF) * sSt[r];
    float* dst = crbuf + ((size_t)b*Nn + n)*Rr;
    ((float4*)dst)[0] = make_float4(simv[0], simv[1], simv[2], simv[3]);
    ((float4*)dst)[1] = make_float4(simv[4], simv[5], simv[6], simv[7]);
}

// ---------------------------------------------------------------- K3b: per-(b,r) softmax over n, in-place on crbuf
__global__ __launch_bounds__(256) void k_crsm(float* __restrict__ crbuf)
{
    __shared__ float s_sim[Nn];
    __shared__ float s_red[256];
    const int b = blockIdx.x >> 3, r = blockIdx.x & 7;
    const int tx = threadIdx.x;
    for (int n = tx; n < Nn; n += 256)
        s_sim[n] = crbuf[((size_t)b*Nn + n)*Rr + r];
    __syncthreads();
    float lm = -3.402823466e38f;
    for (int n = tx; n < Nn; n += 256) lm = fmaxf(lm, s_sim[n]);
    s_red[tx] = lm; __syncthreads();
    for (int s = 128; s > 0; s >>= 1) { if (tx < s) s_red[tx] = fmaxf(s_red[tx], s_red[tx+s]); __syncthreads(); }
    float mx = s_red[0]; __syncthreads();
    float ls = 0.f;
    for (int n = tx; n < Nn; n += 256) ls += expf(s_sim[n] - mx);
    s_red[tx] = ls; __syncthreads();
    for (int s = 128; s > 0; s >>= 1) { if (tx < s) s_red[tx] += s_red[tx+s]; __syncthreads(); }
    float inv = 1.f / s_red[0];
    for (int n = tx; n < Nn; n += 256)
        crbuf[((size_t)b*Nn + n)*Rr + r] = expf(s_sim[n] - mx) * inv;
}

// ---------------------------------------------------------------- K4: O1 = L@M2, O2 partials.
// R12 skeleton; single change: phase-B m2r reads come from GLOBAL (L1-resident 8 KB/block
// region, 64 B-contiguous per row, 8-lane broadcast) -- sM2r staging removed.
// vmcnt counts unchanged and remain exact: m2r loads are younger than the tile stage and
// fully consumed (hence retired, in-order) within their own chunk.
// LDS tile swizzle: row i, physical f4-slot p holds logical quad (p ^ (i&7)).
__global__ __launch_bounds__(256, 2) void k_link(const float* __restrict__ L,
    const float* __restrict__ M2g, float* __restrict__ O1g, float* __restrict__ partg)
{
    __shared__ float4 sTile[2][TI*8];     // 32 KB (epilogue: 4 O1 planes)
    __shared__ float4 sM2c[2][WCH*4];     // 4 KB
    __shared__ float4 sCmb[4*4*33];       // 8.25 KB: [wv][c][chq*8+cq], pad 33

    const int b     = blockIdx.x >> 5;
    const int rem   = blockIdx.x & 31;
    const int tile  = rem >> 1;
    const int chalf = rem & 1;
    const int i0    = tile * TI;
    const int j0    = chalf * (Nn/2);
    const int tx    = threadIdx.x;
    const int wv    = tx >> 6;

    const float* Lb  = L + (size_t)b*Nn*Nn;
    const float* M2b = M2g + (size_t)b*Nn*16;

    const int iq  = tx & 63;           // phase A rows iq, iq+64
    const int cq  = tx & 7;            // phase B col quad 0..7
    const int chq = (tx >> 3) & 3;     // phase B channel quad
    const int rh  = tx >> 5;           // phase B 16-row band 0..7 (bit5 -> xor32 partner)

    auto stageTile = [&](int t) {
        const int tb = t & 1;
        const int jc = j0 + t*WCH;
        #pragma unroll
        for (int k = 0; k < 4; ++k) {
            int s = k*256 + tx;
            int i = s >> 3, cp = s & 7;
            const float* src = Lb + (size_t)(i0 + i)*Nn + jc + 4*(cp ^ (i & 7));
            gload_lds16(src, &sTile[tb][k*256 + (wv<<6)]);
        }
        if (wv >= 2) {
            int s = tx - 128;
            const float* src = M2b + (size_t)(jc + (s>>2))*16 + (s&3)*4;
            gload_lds16(src, &sM2c[tb][(wv-2)<<6]);
        }
    };

    stageTile(0);

    float P0[16], P1[16];
    #pragma unroll
    for (int c = 0; c < 16; ++c) { P0[c] = 0.f; P1[c] = 0.f; }

    #pragma unroll 1
    for (int t = 0; t < NCHL; ++t) {
        const int tb = t & 1;
        __builtin_amdgcn_s_barrier();                       // B1: prev buffer + sCmb free
        __builtin_amdgcn_sched_barrier(0);
        if (t+1 < NCHL) stageTile(t+1);
        if (t == NCHL-1) {
            asm volatile("s_waitcnt vmcnt(0)" ::: "memory");
        } else if (t == 0) {
            if (wv < 2) asm volatile("s_waitcnt vmcnt(4)" ::: "memory");
            else        asm volatile("s_waitcnt vmcnt(5)" ::: "memory");
        } else {
            asm volatile("s_waitcnt vmcnt(5)" ::: "memory");
        }
        __builtin_amdgcn_sched_barrier(0);
        __builtin_amdgcn_s_barrier();                       // B2: tile[tb] staged
        __builtin_amdgcn_sched_barrier(0);

        const float4* tileb = sTile[tb];
        const float4* m2cb  = sM2c[tb];

        // ---- phase A: P[row][c] += L[row,j]*M2c[j][c] over this wave's 8 cols
        #pragma unroll
        for (int jo = 0; jo < 2; ++jo) {
            const int jj4 = wv*2 + jo;
            float4 Lv0 = tileb[iq*8      + (jj4 ^ (iq & 7))];
            float4 Lv1 = tileb[(iq+64)*8 + (jj4 ^ (iq & 7))];
            #pragma unroll
            for (int jj = 0; jj < 4; ++jj) {
                const int j = jj4*4 + jj;
                float4 m0 = m2cb[j*4+0], m1 = m2cb[j*4+1], m2v = m2cb[j*4+2], m3 = m2cb[j*4+3];
                float a0 = (jj==0)?Lv0.x:(jj==1)?Lv0.y:(jj==2)?Lv0.z:Lv0.w;
                float a1 = (jj==0)?Lv1.x:(jj==1)?Lv1.y:(jj==2)?Lv1.z:Lv1.w;
                FMA16(P0, a0, m0, m1, m2v, m3)
                FMA16(P1, a1, m0, m1, m2v, m3)
            }
        }

        // ---- phase B: acc[c][e] += L[i, cq*4+c] * M2[i0+i][chq*4+e] over 16-row band
        // tile from LDS; m2r from GLOBAL (L1-resident 8 KB region)
        {
            float acc[4][4];
            #pragma unroll
            for (int c = 0; c < 4; ++c)
                #pragma unroll
                for (int e = 0; e < 4; ++e) acc[c][e] = 0.f;
            #pragma unroll 8
            for (int ii = 0; ii < 16; ++ii) {
                int i = rh*16 + ii;
                float4 Lq = tileb[i*8 + (cq ^ (i & 7))];
                float4 m  = *(const float4*)(M2b + (size_t)(i0 + i)*16 + chq*4);
                acc[0][0] += Lq.x*m.x; acc[0][1] += Lq.x*m.y; acc[0][2] += Lq.x*m.z; acc[0][3] += Lq.x*m.w;
                acc[1][0] += Lq.y*m.x; acc[1][1] += Lq.y*m.y; acc[1][2] += Lq.y*m.z; acc[1][3] += Lq.y*m.w;
                acc[2][0] += Lq.z*m.x; acc[2][1] += Lq.z*m.y; acc[2][2] += Lq.z*m.z; acc[2][3] += Lq.z*m.w;
                acc[3][0] += Lq.w*m.x; acc[3][1] += Lq.w*m.y; acc[3][2] += Lq.w*m.z; acc[3][3] += Lq.w*m.w;
            }
            // pair-reduce the two 16-row bands within this wave (lane^32)
            #pragma unroll
            for (int c = 0; c < 4; ++c)
                #pragma unroll
                for (int e = 0; e < 4; ++e)
                    acc[c][e] += __shfl_xor(acc[c][e], 32);
            if ((tx & 32) == 0) {   // lanes 0-31 of each wave: consecutive slots, conflict-free
                int slot = tx & 31; // = chq*8 + cq
                #pragma unroll
                for (int c = 0; c < 4; ++c)
                    sCmb[wv*132 + c*33 + slot] =
                        make_float4(acc[c][0], acc[c][1], acc[c][2], acc[c][3]);
            }
        }
        asm volatile("s_waitcnt lgkmcnt(0)" ::: "memory");
        __builtin_amdgcn_sched_barrier(0);
        __builtin_amdgcn_s_barrier();                       // B3: sCmb visible
        __builtin_amdgcn_sched_barrier(0);

        if (tx < 128) {                                     // 4-plane combine + coalesced store
            int col = tx >> 2, cq4 = tx & 3;
            int slot = cq4*8 + (col >> 2), c = col & 3;
            float4 a0 = sCmb[0*132 + c*33 + slot];
            float4 a1 = sCmb[1*132 + c*33 + slot];
            float4 a2 = sCmb[2*132 + c*33 + slot];
            float4 a3 = sCmb[3*132 + c*33 + slot];
            float4 s;
            s.x = a0.x+a1.x+a2.x+a3.x; s.y = a0.y+a1.y+a2.y+a3.y;
            s.z = a0.z+a1.z+a2.z+a3.z; s.w = a0.w+a1.w+a2.w+a3.w;
            float* pbase = partg + (((size_t)(tile*BS + b))*Nn + j0 + t*WCH)*16;
            ((float4*)pbase)[tx] = s;
        }
    }

    // ---- O1 epilogue: combine 4 wave col-groups via LDS planes (reuse sTile)
    __syncthreads();
    float4* planes4 = (float4*)sTile;   // 4 planes: [wv][c4*TI + row]
    #pragma unroll
    for (int c4 = 0; c4 < 4; ++c4) {
        planes4[wv*512 + c4*128 + iq]      = make_float4(P0[c4*4],P0[c4*4+1],P0[c4*4+2],P0[c4*4+3]);
        planes4[wv*512 + c4*128 + iq + 64] = make_float4(P1[c4*4],P1[c4*4+1],P1[c4*4+2],P1[c4*4+3]);
    }
    __syncthreads();
    float4* obase = (float4*)(O1g + ((size_t)(chalf*BS + b)*Nn + i0)*16);
    #pragma unroll
    for (int e = 0; e < 2; ++e) {
        int f = e*256 + tx;
        int row = f >> 2, c4 = f & 3;
        float4 s0 = planes4[0*512 + c4*128 + row];
        float4 s1 = planes4[1*512 + c4*128 + row];
        float4 s2 = planes4[2*512 + c4*128 + row];
        float4 s3 = planes4[3*512 + c4*128 + row];
        float4 s;
        s.x = s0.x+s1.x+s2.x+s3.x; s.y = s0.y+s1.y+s2.y+s3.y;
        s.z = s0.z+s1.z+s2.z+s3.z; s.w = s0.w+s1.w+s2.w+s3.w;
        obase[f] = s;
    }
}

// ---------------------------------------------------------------- K5: finalize bw/fw + modes + read vectors
__global__ void k_read(const float* __restrict__ memnew, const float* __restrict__ O1g,
                       const float* __restrict__ partg, const float* __restrict__ cr,
                       const float* __restrict__ ww, const float* __restrict__ prec,
                       const float* __restrict__ c12, const float* __restrict__ rmodes,
                       float* __restrict__ out)
{
    __shared__ float s_o2[256][17];
    __shared__ float s_o1[256][17];
    __shared__ float s_rw[256][Rr];
    __shared__ float s_rm[Rr*3];
    __shared__ float s_c12[16];
    __shared__ float s_part[2][Ww][Rr];
    int b = blockIdx.x >> 3, slice = blockIdx.x & 7;
    int n0 = slice * 256;
    int tx = threadIdx.x;
    if (tx < Rr*3) s_rm[tx] = rmodes[b*Rr*3 + tx];
    if (tx < 16)   s_c12[tx] = c12[b*16 + tx];
    __syncthreads();
    #pragma unroll
    for (int k = 0; k < 4; ++k) {
        int f = k*256 + tx;
        int n = f >> 2, c4 = f & 3;
        float4 acc = make_float4(0.f,0.f,0.f,0.f);
        for (int t = 0; t < NT; ++t) {
            float4 v = ((const float4*)(partg + ((size_t)(t*BS + b)*Nn + n0)*16))[f];
            acc.x += v.x; acc.y += v.y; acc.z += v.z; acc.w += v.w;
        }
        s_o2[n][c4*4+0] = acc.x; s_o2[n][c4*4+1] = acc.y;
        s_o2[n][c4*4+2] = acc.z; s_o2[n][c4*4+3] = acc.w;
        float4 o1a = ((const float4*)(O1g + ((size_t)(0*BS + b)*Nn + n0)*16))[f];
        float4 o1b = ((const float4*)(O1g + ((size_t)(1*BS + b)*Nn + n0)*16))[f];
        s_o1[n][c4*4+0] = o1a.x+o1b.x; s_o1[n][c4*4+1] = o1a.y+o1b.y;
        s_o1[n][c4*4+2] = o1a.z+o1b.z; s_o1[n][c4*4+3] = o1a.w+o1b.w;
    }
    __syncthreads();
    {
        int n = n0 + tx;
        float wwv = ww[b*Nn + n], pv = prec[b*Nn + n];
        float4 cr0 = *(const float4*)(cr + ((size_t)b*Nn + n)*Rr);
        float4 cr1 = *(const float4*)(cr + ((size_t)b*Nn + n)*Rr + 4);
        float crv[8] = {cr0.x,cr0.y,cr0.z,cr0.w,cr1.x,cr1.y,cr1.z,cr1.w};
        #pragma unroll
        for (int r = 0; r < 8; ++r) {
            float bwv = (1.f - wwv)*s_o1[tx][r] - s_o1[tx][8+r] + wwv*s_c12[r];
            float fwv = (1.f - wwv)*s_o2[tx][r] - s_o2[tx][8+r] + pv*s_c12[8+r];
            s_rw[tx][r] = bwv*s_rm[r*3+0] + crv[r]*s_rm[r*3+1] + fwv*s_rm[r*3+2];
        }
    }
    __syncthreads();
    int w = tx & 127, hh = tx >> 7;
    float acc[Rr] = {0,0,0,0,0,0,0,0};
    for (int nl = hh*128; nl < hh*128 + 128; ++nl) {
        float mval = memnew[(size_t)(n0 + nl)*Ww + w];
        #pragma unroll
        for (int r = 0; r < Rr; ++r) acc[r] += mval * s_rw[nl][r];
    }
    #pragma unroll
    for (int r = 0; r < Rr; ++r) s_part[hh][w][r] = acc[r];
    __syncthreads();
    if (hh == 0) {
        #pragma unroll
        for (int r = 0; r < Rr; ++r)
            unsafeAtomicAdd(&out[(w*Rr + r) + b*Ww*Rr], s_part[0][w][r] + s_part[1][w][r]);
    }
}

// ----------------------------------------------------------------
extern "C" void kernel_launch(void* const* d_in, const int* in_sizes, int n_in,
                              void* d_out, int out_size, void* d_ws, size_t ws_size,
                              hipStream_t stream) {
    const float* mem    = (const float*)d_in[0];
    const float* usage  = (const float*)d_in[1];
    const float* prec   = (const float*)d_in[2];
    const float* Lmat   = (const float*)d_in[3];
    const float* lrw    = (const float*)d_in[4];
    const float* rkeys  = (const float*)d_in[5];
    const float* rstr   = (const float*)d_in[6];
    const float* wkey   = (const float*)d_in[7];
    const float* wstr   = (const float*)d_in[8];
    const float* erasev = (const float*)d_in[9];
    const float* wvec   = (const float*)d_in[10];
    const float* agate  = (const float*)d_in[12];
    const float* wgate  = (const float*)d_in[13];
    const float* rmodes = (const float*)d_in[14];

    float* ws       = (float*)d_ws;
    float* ww_      = ws + OFF_WW;
    float* memnew_  = ws + OFF_MEMNEW;
    float* memnorm_ = ws + OFF_MEMNORM;
    float* cr_      = ws + OFF_CR;
    float* M2_      = ws + OFF_M2;
    float* O1_      = ws + OFF_O1;
    float* c12_     = ws + OFF_C12;
    float* part_    = ws + OFF_PART;
    float* sim_     = ws + OFF_SIM;
    float* outf     = (float*)d_out;

    hipMemsetAsync(outf, 0, (size_t)out_size*sizeof(float), stream);

    k_sim   <<<BS*8,    256, 0, stream>>>(mem, wkey, wstr, sim_);
    k_front <<<BS,      512, 0, stream>>>(usage, sim_, agate, wgate, lrw, prec, ww_, M2_, c12_);
    k_memnew<<<Nn/2,    256, 0, stream>>>(mem, ww_, erasev, wvec, memnew_, memnorm_);
    k_crdot <<<BS*8,    256, 0, stream>>>(memnew_, memnorm_, rkeys, rstr, cr_);
    k_crsm  <<<BS*Rr,   256, 0, stream>>>(cr_);
    k_link  <<<BS*NT*2, 256, 0, stream>>>(Lmat, M2_, O1_, part_);
    k_read  <<<BS*8,    256, 0, stream>>>(memnew_, O1_, part_, cr_, ww_, prec, c12_, rmodes, outf);
}

// Round 14
// 366.142 us; speedup vs baseline: 1.3438x; 1.3438x over previous
//
#include <hip/hip_runtime.h>

#define BS 32
#define Nn 2048
#define Ww 128
#define Rr 8
#define EPSF 1e-8f

#define TI   128     // rows per link tile
#define NT   16      // Nn/TI row tiles
#define WCH  32      // cols per chunk
#define NCHL 32      // chunks per block (col-half = 1024 cols)

// workspace layout (float offsets)
#define OFF_WW      0
#define OFF_MEMNEW  (OFF_WW + BS*Nn)
#define OFF_MEMNORM (OFF_MEMNEW + Nn*Ww)
#define OFF_CR      (OFF_MEMNORM + Nn)
#define OFF_M2      (OFF_CR + BS*Nn*Rr)
#define OFF_O1      (OFF_M2 + BS*Nn*16)             // 2 sets (col halves)
#define OFF_C12     (OFF_O1 + 2*BS*Nn*16)
#define OFF_PART    (OFF_C12 + BS*16)
#define OFF_SIM     (OFF_PART + NT*BS*Nn*16)

__device__ __forceinline__ void gload_lds16(const void* g, void* l) {
    __builtin_amdgcn_global_load_lds((const __attribute__((address_space(1))) void*)g,
                                     (__attribute__((address_space(3))) void*)l, 16, 0, 0);
}

#define FMA16(ACC, LV, M0, M1, M2V, M3) \
    ACC[0]  += (LV)*(M0).x;  ACC[1]  += (LV)*(M0).y;  ACC[2]  += (LV)*(M0).z;  ACC[3]  += (LV)*(M0).w; \
    ACC[4]  += (LV)*(M1).x;  ACC[5]  += (LV)*(M1).y;  ACC[6]  += (LV)*(M1).z;  ACC[7]  += (LV)*(M1).w; \
    ACC[8]  += (LV)*(M2V).x; ACC[9]  += (LV)*(M2V).y; ACC[10] += (LV)*(M2V).z; ACC[11] += (LV)*(M2V).w; \
    ACC[12] += (LV)*(M3).x;  ACC[13] += (LV)*(M3).y;  ACC[14] += (LV)*(M3).z;  ACC[15] += (LV)*(M3).w;

// ---------------------------------------------------------------- K0: write-content similarity (256 blocks)
__global__ __launch_bounds__(256) void k_sim(const float* __restrict__ mem,
    const float* __restrict__ wkey, const float* __restrict__ wstr,
    float* __restrict__ simg)
{
    __shared__ float sWK[Ww];
    const int b = blockIdx.x >> 3, sl = blockIdx.x & 7;
    const int tx = threadIdx.x;
    if (tx < Ww) sWK[tx] = wkey[b*Ww + tx];
    __syncthreads();
    float wn2 = 0.f;
    #pragma unroll
    for (int w = 0; w < Ww; w += 4) {
        float4 k4 = *(const float4*)(&sWK[w]);
        wn2 += k4.x*k4.x + k4.y*k4.y + k4.z*k4.z + k4.w*k4.w;
    }
    const float wn = sqrtf(wn2);
    const float st = wstr[b];
    const int n = sl*256 + tx;
    const float* mrow = mem + (size_t)n*Ww;
    float dot = 0.f, m2 = 0.f;
    #pragma unroll
    for (int w = 0; w < Ww; w += 4) {
        float4 m4 = *(const float4*)(mrow + w);
        float4 k4 = *(const float4*)(&sWK[w]);
        dot += m4.x*k4.x + m4.y*k4.y + m4.z*k4.z + m4.w*k4.w;
        m2  += m4.x*m4.x + m4.y*m4.y + m4.z*m4.z + m4.w*m4.w;
    }
    float denom = fmaxf(sqrtf(m2)*wn, EPSF);
    simg[b*Nn + n] = dot / denom * st;
}

// ---------------------------------------------------------------- K1: sort(u64) + alloc + softmax(sim) + ww + prep
__global__ __launch_bounds__(512) void k_front(const float* __restrict__ usage,
    const float* __restrict__ simg, const float* __restrict__ agate,
    const float* __restrict__ wgate, const float* __restrict__ lrw,
    const float* __restrict__ prec, float* __restrict__ ww_out,
    float* __restrict__ M2, float* __restrict__ c12)
{
    __shared__ unsigned long long sk[Nn];   // 16 KB packed (value_bits<<32)|index
    __shared__ float sAll[Nn];              // 8 KB alloc_sorted
    __shared__ float sSim[Nn];              // 8 KB
    __shared__ float sRed[512];
    __shared__ float sQ[64];
    __shared__ float sC[8][16];
    const int b = blockIdx.x, tx = threadIdx.x;

    #pragma unroll
    for (int m = 0; m < 4; ++m) {
        int i = m*512 + tx;
        sk[i] = ((unsigned long long)__float_as_uint(usage[b*Nn + i]) << 32) | (unsigned)i;
    }
    __syncthreads();
    for (int k = 2; k <= Nn; k <<= 1) {
        for (int j = k >> 1; j > 0; j >>= 1) {
            #pragma unroll
            for (int m = 0; m < 4; ++m) {
                int i = m*512 + tx;
                int ixj = i ^ j;
                if (ixj > i) {
                    bool up = ((i & k) == 0);
                    unsigned long long a = sk[i], c = sk[ixj];
                    if (up ? (a > c) : (a < c)) { sk[i] = c; sk[ixj] = a; }
                }
            }
            __syncthreads();
        }
    }
    {
        float p = 1.f;
        #pragma unroll
        for (int e = 0; e < 4; ++e)
            p *= __uint_as_float((unsigned)(sk[tx*4 + e] >> 32));
        sRed[tx] = p;
        __syncthreads();
        if (tx < 64) {
            float q = 1.f;
            #pragma unroll
            for (int e = 0; e < 8; ++e) q *= sRed[tx*8 + e];
            sQ[tx] = q;
        }
        __syncthreads();
        if (tx == 0) {
            float run = 1.f;
            for (int s = 0; s < 64; ++s) { float t = sQ[s]; sQ[s] = run; run *= t; }
        }
        __syncthreads();
        float run = sQ[tx >> 3];
        for (int s = (tx & ~7); s < tx; ++s) run *= sRed[s];
        #pragma unroll
        for (int e = 0; e < 4; ++e) {
            float v = __uint_as_float((unsigned)(sk[tx*4 + e] >> 32));
            sAll[tx*4 + e] = (1.f - v) * run;
            run *= v;
        }
    }
    #pragma unroll
    for (int m = 0; m < 4; ++m) {
        int n = m*512 + tx;
        sSim[n] = simg[b*Nn + n];
    }
    __syncthreads();
    float allocr[4];
    #pragma unroll
    for (int m = 0; m < 4; ++m) {
        int i = m*512 + tx;
        allocr[m] = sAll[(unsigned)(sk[i] & 0xffffffffu)];
    }
    float lm = -3.402823466e38f;
    #pragma unroll
    for (int m = 0; m < 4; ++m) lm = fmaxf(lm, sSim[m*512 + tx]);
    sRed[tx] = lm; __syncthreads();
    for (int s = 256; s > 0; s >>= 1) { if (tx < s) sRed[tx] = fmaxf(sRed[tx], sRed[tx+s]); __syncthreads(); }
    float mx = sRed[0]; __syncthreads();
    float ls = 0.f;
    #pragma unroll
    for (int m = 0; m < 4; ++m) ls += expf(sSim[m*512 + tx] - mx);
    sRed[tx] = ls; __syncthreads();
    for (int s = 256; s > 0; s >>= 1) { if (tx < s) sRed[tx] += sRed[tx+s]; __syncthreads(); }
    float inv = 1.f / sRed[0];
    float ag = agate[b], wg = wgate[b];
    float wwr[4];
    #pragma unroll
    for (int m = 0; m < 4; ++m) {
        int n = m*512 + tx;
        float cw = expf(sSim[n] - mx) * inv;
        wwr[m] = wg * (ag * allocr[m] + (1.f - ag) * cw);
        ww_out[b*Nn + n] = wwr[m];
    }

    float c1p[8] = {0,0,0,0,0,0,0,0};
    float c2p[8] = {0,0,0,0,0,0,0,0};
    #pragma unroll
    for (int m = 0; m < 4; ++m) {
        int j = m*512 + tx;
        size_t jb = (size_t)b*Nn + j;
        float4 a  = *(const float4*)(lrw + jb*Rr);
        float4 b4 = *(const float4*)(lrw + jb*Rr + 4);
        float w = wwr[m], pv = prec[jb];
        float* dst = M2 + jb*16;
        ((float4*)dst)[0] = a;
        ((float4*)dst)[1] = b4;
        ((float4*)dst)[2] = make_float4(a.x*w,  a.y*w,  a.z*w,  a.w*w);
        ((float4*)dst)[3] = make_float4(b4.x*w, b4.y*w, b4.z*w, b4.w*w);
        c1p[0] += pv*a.x;  c1p[1] += pv*a.y;  c1p[2] += pv*a.z;  c1p[3] += pv*a.w;
        c1p[4] += pv*b4.x; c1p[5] += pv*b4.y; c1p[6] += pv*b4.z; c1p[7] += pv*b4.w;
        c2p[0] += w*a.x;   c2p[1] += w*a.y;   c2p[2] += w*a.z;   c2p[3] += w*a.w;
        c2p[4] += w*b4.x;  c2p[5] += w*b4.y;  c2p[6] += w*b4.z;  c2p[7] += w*b4.w;
    }
    #pragma unroll
    for (int r = 0; r < 8; ++r) {
        float v1 = c1p[r], v2 = c2p[r];
        #pragma unroll
        for (int m = 1; m < 64; m <<= 1) { v1 += __shfl_xor(v1, m); v2 += __shfl_xor(v2, m); }
        c1p[r] = v1; c2p[r] = v2;
    }
    int wv = tx >> 6;
    if ((tx & 63) == 0) {
        #pragma unroll
        for (int r = 0; r < 8; ++r) { sC[wv][r] = c1p[r]; sC[wv][8+r] = c2p[r]; }
    }
    __syncthreads();
    if (tx < 16) {
        float s = 0.f;
        #pragma unroll
        for (int w8 = 0; w8 < 8; ++w8) s += sC[w8][tx];
        c12[b*16 + tx] = s;
    }
}

// ---------------------------------------------------------------- K2: memory_new + row norms
__global__ void k_memnew(const float* __restrict__ mem, const float* __restrict__ ww,
                         const float* __restrict__ erasev, const float* __restrict__ wvec,
                         float* __restrict__ memnew, float* __restrict__ memnorm)
{
    __shared__ float s_red[2][Ww];
    int tx = threadIdx.x;
    int h = tx >> 7, w = tx & 127;
    int n = blockIdx.x * 2 + h;
    float accE = 0.f, accA = 0.f;
    for (int b = 0; b < BS; ++b) {
        float wwv = ww[b*Nn + n];
        accE += wwv * erasev[b*Ww + w];
        accA += wwv * wvec[b*Ww + w];
    }
    const float inv = 1.f / (float)BS;
    float m = mem[(size_t)n*Ww + w];
    float outv = m * (1.f - accE*inv) + accA*inv;
    memnew[(size_t)n*Ww + w] = outv;
    s_red[h][w] = outv*outv;
    __syncthreads();
    for (int s = 64; s > 0; s >>= 1) { if (w < s) s_red[h][w] += s_red[h][w+s]; __syncthreads(); }
    if (w == 0) memnorm[n] = sqrtf(s_red[h][0]);
}

// ---------------------------------------------------------------- K3a: read-sim dots (memnew read ONCE per block)
__global__ __launch_bounds__(256) void k_crdot(const float* __restrict__ memnew,
    const float* __restrict__ memnorm, const float* __restrict__ rkeys,
    const float* __restrict__ rstr, float* __restrict__ crbuf)
{
    __shared__ float sK[Ww][Rr];    // 4 KB keys
    __shared__ float sKn[Rr];
    __shared__ float sSt[Rr];
    const int b = blockIdx.x >> 3, sl = blockIdx.x & 7;
    const int tx = threadIdx.x;
    for (int k = tx; k < Ww*Rr; k += 256) {
        int w = k >> 3, r = k & 7;
        sK[w][r] = rkeys[((size_t)b*Ww + w)*Rr + r];
    }
    if (tx < Rr) sSt[tx] = rstr[b*Rr + tx];
    __syncthreads();
    if (tx < Rr) {
        float kn2 = 0.f;
        for (int w = 0; w < Ww; ++w) { float k = sK[w][tx]; kn2 += k*k; }
        sKn[tx] = sqrtf(kn2);
    }
    __syncthreads();
    const int n = sl*256 + tx;
    const float* mrow = memnew + (size_t)n*Ww;
    float dot[8] = {0,0,0,0,0,0,0,0};
    #pragma unroll 4
    for (int w = 0; w < Ww; w += 4) {
        float4 m4 = *(const float4*)(mrow + w);
        #pragma unroll
        for (int l = 0; l < 4; ++l) {
            float mv = (l==0)?m4.x:(l==1)?m4.y:(l==2)?m4.z:m4.w;
            float4 k0 = *(const float4*)(&sK[w+l][0]);
            float4 k1 = *(const float4*)(&sK[w+l][4]);
            dot[0] += mv*k0.x; dot[1] += mv*k0.y; dot[2] += mv*k0.z; dot[3] += mv*k0.w;
            dot[4] += mv*k1.x; dot[5] += mv*k1.y; dot[6] += mv*k1.z; dot[7] += mv*k1.w;
        }
    }
    const float mn = memnorm[n];
    float simv[8];
    #pragma unroll
    for (int r = 0; r < 8; ++r)
        simv[r] = dot[r] / fmaxf(mn*sKn[r], EPSF) * sSt[r];
    float* dst = crbuf + ((size_t)b*Nn + n)*Rr;
    ((float4*)dst)[0] = make_float4(simv[0], simv[1], simv[2], simv[3]);
    ((float4*)dst)[1] = make_float4(simv[4], simv[5], simv[6], simv[7]);
}

// ---------------------------------------------------------------- K3b: per-(b,r) softmax over n, in-place on crbuf
__global__ __launch_bounds__(256) void k_crsm(float* __restrict__ crbuf)
{
    __shared__ float s_sim[Nn];
    __shared__ float s_red[256];
    const int b = blockIdx.x >> 3, r = blockIdx.x & 7;
    const int tx = threadIdx.x;
    for (int n = tx; n < Nn; n += 256)
        s_sim[n] = crbuf[((size_t)b*Nn + n)*Rr + r];
    __syncthreads();
    float lm = -3.402823466e38f;
    for (int n = tx; n < Nn; n += 256) lm = fmaxf(lm, s_sim[n]);
    s_red[tx] = lm; __syncthreads();
    for (int s = 128; s > 0; s >>= 1) { if (tx < s) s_red[tx] = fmaxf(s_red[tx], s_red[tx+s]); __syncthreads(); }
    float mx = s_red[0]; __syncthreads();
    float ls = 0.f;
    for (int n = tx; n < Nn; n += 256) ls += expf(s_sim[n] - mx);
    s_red[tx] = ls; __syncthreads();
    for (int s = 128; s > 0; s >>= 1) { if (tx < s) s_red[tx] += s_red[tx+s]; __syncthreads(); }
    float inv = 1.f / s_red[0];
    for (int n = tx; n < Nn; n += 256)
        crbuf[((size_t)b*Nn + n)*Rr + r] = expf(s_sim[n] - mx) * inv;
}

// ---------------------------------------------------------------- K4: O1 = L@M2, O2 partials. (exact R12 version)
__global__ __launch_bounds__(256, 2) void k_link(const float* __restrict__ L,
    const float* __restrict__ M2g, float* __restrict__ O1g, float* __restrict__ partg)
{
    __shared__ float4 sTile[2][TI*8];     // 32 KB (epilogue: 4 O1 planes)
    __shared__ float4 sM2c[2][WCH*4];     // 4 KB
    __shared__ float4 sM2r[TI*4];         // 8 KB
    __shared__ float4 sCmb[4*4*33];       // 8.25 KB: [wv][c][chq*8+cq], pad 33

    const int b     = blockIdx.x >> 5;
    const int rem   = blockIdx.x & 31;
    const int tile  = rem >> 1;
    const int chalf = rem & 1;
    const int i0    = tile * TI;
    const int j0    = chalf * (Nn/2);
    const int tx    = threadIdx.x;
    const int wv    = tx >> 6;

    const float* Lb  = L + (size_t)b*Nn*Nn;
    const float* M2b = M2g + (size_t)b*Nn*16;

    const int iq  = tx & 63;           // phase A rows iq, iq+64
    const int cq  = tx & 7;            // phase B col quad 0..7
    const int chq = (tx >> 3) & 3;     // phase B channel quad
    const int rh  = tx >> 5;           // phase B 16-row band 0..7 (bit5 -> xor32 partner)

    auto stageTile = [&](int t) {
        const int tb = t & 1;
        const int jc = j0 + t*WCH;
        #pragma unroll
        for (int k = 0; k < 4; ++k) {
            int s = k*256 + tx;
            int i = s >> 3, cp = s & 7;
            const float* src = Lb + (size_t)(i0 + i)*Nn + jc + 4*(cp ^ (i & 7));
            gload_lds16(src, &sTile[tb][k*256 + (wv<<6)]);
        }
        if (wv >= 2) {
            int s = tx - 128;
            const float* src = M2b + (size_t)(jc + (s>>2))*16 + (s&3)*4;
            gload_lds16(src, &sM2c[tb][(wv-2)<<6]);
        }
    };

    // prologue: sM2r (rows of this tile) + first chunk
    #pragma unroll
    for (int k = 0; k < 2; ++k) {
        int s = k*256 + tx;
        const float* src = M2b + (size_t)(i0 + (s>>2))*16 + (s&3)*4;
        gload_lds16(src, &sM2r[k*256 + (wv<<6)]);
    }
    stageTile(0);

    float P0[16], P1[16];
    #pragma unroll
    for (int c = 0; c < 16; ++c) { P0[c] = 0.f; P1[c] = 0.f; }

    #pragma unroll 1
    for (int t = 0; t < NCHL; ++t) {
        const int tb = t & 1;
        __builtin_amdgcn_s_barrier();                       // B1: prev buffer + sCmb free
        __builtin_amdgcn_sched_barrier(0);
        if (t+1 < NCHL) stageTile(t+1);
        if (t == NCHL-1) {
            asm volatile("s_waitcnt vmcnt(0)" ::: "memory");
        } else if (t == 0) {
            if (wv < 2) asm volatile("s_waitcnt vmcnt(4)" ::: "memory");
            else        asm volatile("s_waitcnt vmcnt(5)" ::: "memory");
        } else {
            asm volatile("s_waitcnt vmcnt(5)" ::: "memory");
        }
        __builtin_amdgcn_sched_barrier(0);
        __builtin_amdgcn_s_barrier();                       // B2: tile[tb] staged
        __builtin_amdgcn_sched_barrier(0);

        const float4* tileb = sTile[tb];
        const float4* m2cb  = sM2c[tb];

        // ---- phase A: P[row][c] += L[row,j]*M2c[j][c] over this wave's 8 cols
        #pragma unroll
        for (int jo = 0; jo < 2; ++jo) {
            const int jj4 = wv*2 + jo;
            float4 Lv0 = tileb[iq*8      + (jj4 ^ (iq & 7))];
            float4 Lv1 = tileb[(iq+64)*8 + (jj4 ^ (iq & 7))];
            #pragma unroll
            for (int jj = 0; jj < 4; ++jj) {
                const int j = jj4*4 + jj;
                float4 m0 = m2cb[j*4+0], m1 = m2cb[j*4+1], m2v = m2cb[j*4+2], m3 = m2cb[j*4+3];
                float a0 = (jj==0)?Lv0.x:(jj==1)?Lv0.y:(jj==2)?Lv0.z:Lv0.w;
                float a1 = (jj==0)?Lv1.x:(jj==1)?Lv1.y:(jj==2)?Lv1.z:Lv1.w;
                FMA16(P0, a0, m0, m1, m2v, m3)
                FMA16(P1, a1, m0, m1, m2v, m3)
            }
        }

        // ---- phase B: acc[c][e] += L[i, cq*4+c] * M2r[i][chq*4+e] over 16-row band
        {
            float acc[4][4];
            #pragma unroll
            for (int c = 0; c < 4; ++c)
                #pragma unroll
                for (int e = 0; e < 4; ++e) acc[c][e] = 0.f;
            #pragma unroll 8
            for (int ii = 0; ii < 16; ++ii) {
                int i = rh*16 + ii;
                float4 Lq = tileb[i*8 + (cq ^ (i & 7))];
                float4 m  = sM2r[i*4 + chq];
                acc[0][0] += Lq.x*m.x; acc[0][1] += Lq.x*m.y; acc[0][2] += Lq.x*m.z; acc[0][3] += Lq.x*m.w;
                acc[1][0] += Lq.y*m.x; acc[1][1] += Lq.y*m.y; acc[1][2] += Lq.y*m.z; acc[1][3] += Lq.y*m.w;
                acc[2][0] += Lq.z*m.x; acc[2][1] += Lq.z*m.y; acc[2][2] += Lq.z*m.z; acc[2][3] += Lq.z*m.w;
                acc[3][0] += Lq.w*m.x; acc[3][1] += Lq.w*m.y; acc[3][2] += Lq.w*m.z; acc[3][3] += Lq.w*m.w;
            }
            // pair-reduce the two 16-row bands within this wave (lane^32)
            #pragma unroll
            for (int c = 0; c < 4; ++c)
                #pragma unroll
                for (int e = 0; e < 4; ++e)
                    acc[c][e] += __shfl_xor(acc[c][e], 32);
            if ((tx & 32) == 0) {   // lanes 0-31 of each wave: consecutive slots, conflict-free
                int slot = tx & 31; // = chq*8 + cq
                #pragma unroll
                for (int c = 0; c < 4; ++c)
                    sCmb[wv*132 + c*33 + slot] =
                        make_float4(acc[c][0], acc[c][1], acc[c][2], acc[c][3]);
            }
        }
        asm volatile("s_waitcnt lgkmcnt(0)" ::: "memory");
        __builtin_amdgcn_sched_barrier(0);
        __builtin_amdgcn_s_barrier();                       // B3: sCmb visible
        __builtin_amdgcn_sched_barrier(0);

        if (tx < 128) {                                     // 4-plane combine + coalesced store
            int col = tx >> 2, cq4 = tx & 3;
            int slot = cq4*8 + (col >> 2), c = col & 3;
            float4 a0 = sCmb[0*132 + c*33 + slot];
            float4 a1 = sCmb[1*132 + c*33 + slot];
            float4 a2 = sCmb[2*132 + c*33 + slot];
            float4 a3 = sCmb[3*132 + c*33 + slot];
            float4 s;
            s.x = a0.x+a1.x+a2.x+a3.x; s.y = a0.y+a1.y+a2.y+a3.y;
            s.z = a0.z+a1.z+a2.z+a3.z; s.w = a0.w+a1.w+a2.w+a3.w;
            float* pbase = partg + (((size_t)(tile*BS + b))*Nn + j0 + t*WCH)*16;
            ((float4*)pbase)[tx] = s;
        }
    }

    // ---- O1 epilogue: combine 4 wave col-groups via LDS planes (reuse sTile)
    __syncthreads();
    float4* planes4 = (float4*)sTile;   // 4 planes: [wv][c4*TI + row]
    #pragma unroll
    for (int c4 = 0; c4 < 4; ++c4) {
        planes4[wv*512 + c4*128 + iq]      = make_float4(P0[c4*4],P0[c4*4+1],P0[c4*4+2],P0[c4*4+3]);
        planes4[wv*512 + c4*128 + iq + 64] = make_float4(P1[c4*4],P1[c4*4+1],P1[c4*4+2],P1[c4*4+3]);
    }
    __syncthreads();
    float4* obase = (float4*)(O1g + ((size_t)(chalf*BS + b)*Nn + i0)*16);
    #pragma unroll
    for (int e = 0; e < 2; ++e) {
        int f = e*256 + tx;
        int row = f >> 2, c4 = f & 3;
        float4 s0 = planes4[0*512 + c4*128 + row];
        float4 s1 = planes4[1*512 + c4*128 + row];
        float4 s2 = planes4[2*512 + c4*128 + row];
        float4 s3 = planes4[3*512 + c4*128 + row];
        float4 s;
        s.x = s0.x+s1.x+s2.x+s3.x; s.y = s0.y+s1.y+s2.y+s3.y;
        s.z = s0.z+s1.z+s2.z+s3.z; s.w = s0.w+s1.w+s2.w+s3.w;
        obase[f] = s;
    }
}

// ---------------------------------------------------------------- K5: finalize bw/fw + modes + read vectors
__global__ void k_read(const float* __restrict__ memnew, const float* __restrict__ O1g,
                       const float* __restrict__ partg, const float* __restrict__ cr,
                       const float* __restrict__ ww, const float* __restrict__ prec,
                       const float* __restrict__ c12, const float* __restrict__ rmodes,
                       float* __restrict__ out)
{
    __shared__ float s_o2[256][17];
    __shared__ float s_o1[256][17];
    __shared__ float s_rw[256][Rr];
    __shared__ float s_rm[Rr*3];
    __shared__ float s_c12[16];
    __shared__ float s_part[2][Ww][Rr];
    int b = blockIdx.x >> 3, slice = blockIdx.x & 7;
    int n0 = slice * 256;
    int tx = threadIdx.x;
    if (tx < Rr*3) s_rm[tx] = rmodes[b*Rr*3 + tx];
    if (tx < 16)   s_c12[tx] = c12[b*16 + tx];
    __syncthreads();
    #pragma unroll
    for (int k = 0; k < 4; ++k) {
        int f = k*256 + tx;
        int n = f >> 2, c4 = f & 3;
        float4 acc = make_float4(0.f,0.f,0.f,0.f);
        for (int t = 0; t < NT; ++t) {
            float4 v = ((const float4*)(partg + ((size_t)(t*BS + b)*Nn + n0)*16))[f];
            acc.x += v.x; acc.y += v.y; acc.z += v.z; acc.w += v.w;
        }
        s_o2[n][c4*4+0] = acc.x; s_o2[n][c4*4+1] = acc.y;
        s_o2[n][c4*4+2] = acc.z; s_o2[n][c4*4+3] = acc.w;
        float4 o1a = ((const float4*)(O1g + ((size_t)(0*BS + b)*Nn + n0)*16))[f];
        float4 o1b = ((const float4*)(O1g + ((size_t)(1*BS + b)*Nn + n0)*16))[f];
        s_o1[n][c4*4+0] = o1a.x+o1b.x; s_o1[n][c4*4+1] = o1a.y+o1b.y;
        s_o1[n][c4*4+2] = o1a.z+o1b.z; s_o1[n][c4*4+3] = o1a.w+o1b.w;
    }
    __syncthreads();
    {
        int n = n0 + tx;
        float wwv = ww[b*Nn + n], pv = prec[b*Nn + n];
        float4 cr0 = *(const float4*)(cr + ((size_t)b*Nn + n)*Rr);
        float4 cr1 = *(const float4*)(cr + ((size_t)b*Nn + n)*Rr + 4);
        float crv[8] = {cr0.x,cr0.y,cr0.z,cr0.w,cr1.x,cr1.y,cr1.z,cr1.w};
        #pragma unroll
        for (int r = 0; r < 8; ++r) {
            float bwv = (1.f - wwv)*s_o1[tx][r] - s_o1[tx][8+r] + wwv*s_c12[r];
            float fwv = (1.f - wwv)*s_o2[tx][r] - s_o2[tx][8+r] + pv*s_c12[8+r];
            s_rw[tx][r] = bwv*s_rm[r*3+0] + crv[r]*s_rm[r*3+1] + fwv*s_rm[r*3+2];
        }
    }
    __syncthreads();
    int w = tx & 127, hh = tx >> 7;
    float acc[Rr] = {0,0,0,0,0,0,0,0};
    for (int nl = hh*128; nl < hh*128 + 128; ++nl) {
        float mval = memnew[(size_t)(n0 + nl)*Ww + w];
        #pragma unroll
        for (int r = 0; r < Rr; ++r) acc[r] += mval * s_rw[nl][r];
    }
    #pragma unroll
    for (int r = 0; r < Rr; ++r) s_part[hh][w][r] = acc[r];
    __syncthreads();
    if (hh == 0) {
        #pragma unroll
        for (int r = 0; r < Rr; ++r)
            unsafeAtomicAdd(&out[(w*Rr + r) + b*Ww*Rr], s_part[0][w][r] + s_part[1][w][r]);
    }
}

// ----------------------------------------------------------------
extern "C" void kernel_launch(void* const* d_in, const int* in_sizes, int n_in,
                              void* d_out, int out_size, void* d_ws, size_t ws_size,
                              hipStream_t stream) {
    const float* mem    = (const float*)d_in[0];
    const float* usage  = (const float*)d_in[1];
    const float* prec   = (const float*)d_in[2];
    const float* Lmat   = (const float*)d_in[3];
    const float* lrw    = (const float*)d_in[4];
    const float* rkeys  = (const float*)d_in[5];
    const float* rstr   = (const float*)d_in[6];
    const float* wkey   = (const float*)d_in[7];
    const float* wstr   = (const float*)d_in[8];
    const float* erasev = (const float*)d_in[9];
    const float* wvec   = (const float*)d_in[10];
    const float* agate  = (const float*)d_in[12];
    const float* wgate  = (const float*)d_in[13];
    const float* rmodes = (const float*)d_in[14];

    float* ws       = (float*)d_ws;
    float* ww_      = ws + OFF_WW;
    float* memnew_  = ws + OFF_MEMNEW;
    float* memnorm_ = ws + OFF_MEMNORM;
    float* cr_      = ws + OFF_CR;
    float* M2_      = ws + OFF_M2;
    float* O1_      = ws + OFF_O1;
    float* c12_     = ws + OFF_C12;
    float* part_    = ws + OFF_PART;
    float* sim_     = ws + OFF_SIM;
    float* outf     = (float*)d_out;

    hipMemsetAsync(outf, 0, (size_t)out_size*sizeof(float), stream);

    k_sim   <<<BS*8,    256, 0, stream>>>(mem, wkey, wstr, sim_);
    k_front <<<BS,      512, 0, stream>>>(usage, sim_, agate, wgate, lrw, prec, ww_, M2_, c12_);
    k_memnew<<<Nn/2,    256, 0, stream>>>(mem, ww_, erasev, wvec, memnew_, memnorm_);
    k_crdot <<<BS*8,    256, 0, stream>>>(memnew_, memnorm_, rkeys, rstr, cr_);
    k_crsm  <<<BS*Rr,   256, 0, stream>>>(cr_);
    k_link  <<<BS*NT*2, 256, 0, stream>>>(Lmat, M2_, O1_, part_);
    k_read  <<<BS*8,    256, 0, stream>>>(memnew_, O1_, part_, cr_, ww_, prec, c12_, rmodes, outf);
}